// Round 8
// baseline (29.654 us; speedup 1.0000x reference)
//
#include <hip/hip_runtime.h>

// Sample_PDF: R=65536 rays, N=64, F=128. One wave per 8 rays, LDS-free,
// software-pipelined: ray i+1's global loads are issued while ray i computes,
// so HBM latency hides under compute instead of relying on TLP alone.
// DPP scan + per-bin linear coeffs + 3 readlane + 3 bpermute search levels,
// ballot path for s[128] (hoisted), one non-temporal dwordx4 store per lane.

#define WAVES_PER_BLOCK 4
#define RAYS_PER_WAVE 8
#define DPP_WAVE_SHL1 0x130
#define DPP_WAVE_SHR1 0x138

typedef float fvec4 __attribute__((ext_vector_type(4)));

template <int CTRL, int ROW_MASK>
__device__ __forceinline__ float dpp_add(float x) {
    int sh = __builtin_amdgcn_update_dpp(0, __float_as_int(x), CTRL, ROW_MASK, 0xf, false);
    return x + __int_as_float(sh);
}

// lane i gets src from lane i-1 (SHR) / i+1 (SHL); boundary lane gets `old`.
template <int CTRL>
__device__ __forceinline__ float dpp_old_f(float old, float src) {
    return __int_as_float(__builtin_amdgcn_update_dpp(
        __float_as_int(old), __float_as_int(src), CTRL, 0xf, 0xf, false));
}

__device__ __forceinline__ float readlane_f(float v, int lane) {
    return __int_as_float(__builtin_amdgcn_readlane(__float_as_int(v), lane));
}

__device__ __forceinline__ float bperm(int byteaddr, float v) {
    return __int_as_float(__builtin_amdgcn_ds_bpermute(byteaddr, __float_as_int(v)));
}

// cdf[m] (m=1..64) lives at lane m-1 of cdfv. Returns 4*lo with
// cdf[lo] <= uu < cdf[lo+1], lo in [0,63].
__device__ __forceinline__ int search6(float uu, float cdfv,
                                       float c8, float c16, float c24, float c32,
                                       float c40, float c48, float c56) {
    bool g1 = (c32 <= uu);
    int loB = g1 ? 128 : 0;
    float cA = g1 ? c48 : c16;
    bool g2 = (cA <= uu);
    loB += g2 ? 64 : 0;
    float pL = g1 ? c40 : c8;
    float pH = g1 ? c56 : c24;
    float cB = g2 ? pH : pL;
    loB += (cB <= uu) ? 32 : 0;
    float c = bperm(loB + 12, cdfv);   // cdf[lo+4] @ lane lo+3
    loB += (c <= uu) ? 16 : 0;
    c = bperm(loB + 4, cdfv);          // cdf[lo+2] @ lane lo+1
    loB += (c <= uu) ? 8 : 0;
    c = bperm(loB, cdfv);              // cdf[lo+1] @ lane lo
    loB += (c <= uu) ? 4 : 0;
    return loB;
}

__global__ __launch_bounds__(64 * WAVES_PER_BLOCK)
void sample_pdf_kernel(const float* __restrict__ weights,   // [R,64]
                       const float* __restrict__ t_inters,  // [R,64,2]
                       const float* __restrict__ u,         // [R,129]
                       float* __restrict__ out,             // [R,128,2]
                       int R) {
    const int lane = threadIdx.x & 63;
    const int wave = threadIdx.x >> 6;
    const int ray0 = (blockIdx.x * WAVES_PER_BLOCK + wave) * RAYS_PER_WAVE;

    // ---- prefetch ray0's inputs
    float  w_n  = weights[(long)ray0 * 64 + lane];
    float2 ti_n = ((const float2*)t_inters)[(long)ray0 * 64 + lane];
    const float* ub_n = u + (long)ray0 * 129;
    float u0_n = ub_n[2 * lane];
    float u1_n = ub_n[2 * lane + 1];
    float u2_n = ub_n[128];

    #pragma unroll
    for (int i = 0; i < RAYS_PER_WAVE; ++i) {
        const int ray = ray0 + i;
        // consume prefetched values
        float  w  = w_n;
        float2 ti = ti_n;
        float  u0 = u0_n, u1 = u1_n, u2 = u2_n;

        // issue next ray's loads NOW (independent of this ray's chain)
        if (i + 1 < RAYS_PER_WAVE) {
            const int rn = ray + 1;
            w_n  = weights[(long)rn * 64 + lane];
            ti_n = ((const float2*)t_inters)[(long)rn * 64 + lane];
            const float* ub = u + (long)rn * 129;
            u0_n = ub[2 * lane];
            u1_n = ub[2 * lane + 1];
            u2_n = ub[128];
        }

        // maxblur: neighbors via wave shifts, edge clamp via DPP `old`
        float wm1 = dpp_old_f<DPP_WAVE_SHR1>(w, w);       // w[l-1], lane0 -> w
        float wp1 = dpp_old_f<DPP_WAVE_SHL1>(w, w);       // w[l+1], lane63 -> w
        float w2 = (fmaxf(wm1, w) + fmaxf(w, wp1)) * 0.5f + 0.01f;

        // inclusive scan (canonical gfx9 DPP, 6 ops)
        float scan = w2;
        scan = dpp_add<0x111, 0xf>(scan);  // row_shr:1
        scan = dpp_add<0x112, 0xf>(scan);  // row_shr:2
        scan = dpp_add<0x114, 0xf>(scan);  // row_shr:4
        scan = dpp_add<0x118, 0xf>(scan);  // row_shr:8
        scan = dpp_add<0x142, 0xa>(scan);  // row_bcast:15
        scan = dpp_add<0x143, 0xc>(scan);  // row_bcast:31

        // padding term is provably 0 (wsum >= 0.64 >> 1e-5); fmin(1,.) only
        // trims <=1e-7 rounding excess -> both dropped.
        float wsum = readlane_f(scan, 63);
        float cdfv = scan * __builtin_amdgcn_rcpf(wsum);
        if (lane == 63) cdfv = 1.0f;       // cdf[64] = 1 exactly (u < 1 always)

        // per-bin linear coeffs: sample(u in bin l) = A[l] + B[l]*u
        float clo = dpp_old_f<DPP_WAVE_SHR1>(0.0f, cdfv);   // cdf[l], lane0 -> 0
        float nx  = dpp_old_f<DPP_WAVE_SHL1>(ti.y, ti.x);   // t_vals[l+1], lane63 -> ti.y
        float dt  = nx - ti.x;
        float Bv  = dt * __builtin_amdgcn_rcpf(cdfv - clo); // gap > 0 always
        float Av  = ti.x - clo * Bv;

        // s[128] (hoisted off the store's tail): ballot + popcount, scalar
        unsigned long long mask = __ballot(cdfv <= u2);     // lane63 never set
        int p = __popcll(mask);                             // = lo2 in [0,63]
        float s2 = readlane_f(Av, p) + readlane_f(Bv, p) * u2;

        // probes for the top 3 search levels (SGPR broadcasts)
        float c8  = readlane_f(cdfv, 7),  c16 = readlane_f(cdfv, 15);
        float c24 = readlane_f(cdfv, 23), c32 = readlane_f(cdfv, 31);
        float c40 = readlane_f(cdfv, 39), c48 = readlane_f(cdfv, 47);
        float c56 = readlane_f(cdfv, 55);

        int lA = search6(u0, cdfv, c8, c16, c24, c32, c40, c48, c56);
        int lB = search6(u1, cdfv, c8, c16, c24, c32, c40, c48, c56);
        float s_a = bperm(lA, Av) + bperm(lA, Bv) * u0;     // s[2l]
        float s_b = bperm(lB, Av) + bperm(lB, Bv) * u1;     // s[2l+1]

        // s[2l+2] = next lane's s_a; lane63 -> s2 via DPP old
        float s_an = dpp_old_f<DPP_WAVE_SHL1>(s2, s_a);

        // one non-temporal dwordx4 per lane
        fvec4 o4 = { s_a, s_b, s_b, s_an };
        __builtin_nontemporal_store(o4, &((fvec4*)out)[(long)ray * 64 + lane]);
    }
}

extern "C" void kernel_launch(void* const* d_in, const int* in_sizes, int n_in,
                              void* d_out, int out_size, void* d_ws, size_t ws_size,
                              hipStream_t stream) {
    const float* weights  = (const float*)d_in[0];
    const float* t_inters = (const float*)d_in[1];
    const float* u        = (const float*)d_in[2];
    float* out            = (float*)d_out;

    const int R = in_sizes[0] / 64;                         // 65536
    const int rays_per_block = WAVES_PER_BLOCK * RAYS_PER_WAVE;
    const int grid = (R + rays_per_block - 1) / rays_per_block;   // 2048
    sample_pdf_kernel<<<grid, 64 * WAVES_PER_BLOCK, 0, stream>>>(weights, t_inters, u, out, R);
}

// Round 9
// 27.160 us; speedup vs baseline: 1.0918x; 1.0918x over previous
//
#include <hip/hip_runtime.h>

// Sample_PDF: R=65536 rays, N=64, F=128. TWO rays per wave, chains fully
// interleaved (register-duplicated) so every dependent-latency hop of ray A
// (scan DPP, readlane, 3-level bpermute search) is filled by ray B's work.
// LDS-free; per-bin linear coeffs; ballot path for s[128]; nt dwordx4 store.

#define WAVES_PER_BLOCK 4
#define DPP_WAVE_SHL1 0x130
#define DPP_WAVE_SHR1 0x138

typedef float fvec4 __attribute__((ext_vector_type(4)));

template <int CTRL, int ROW_MASK>
__device__ __forceinline__ float dpp_add(float x) {
    int sh = __builtin_amdgcn_update_dpp(0, __float_as_int(x), CTRL, ROW_MASK, 0xf, false);
    return x + __int_as_float(sh);
}

// lane i gets src from lane i-1 (SHR) / i+1 (SHL); boundary lane gets `old`.
template <int CTRL>
__device__ __forceinline__ float dpp_old_f(float old, float src) {
    return __int_as_float(__builtin_amdgcn_update_dpp(
        __float_as_int(old), __float_as_int(src), CTRL, 0xf, 0xf, false));
}

__device__ __forceinline__ float readlane_f(float v, int lane) {
    return __int_as_float(__builtin_amdgcn_readlane(__float_as_int(v), lane));
}

__device__ __forceinline__ float bperm(int byteaddr, float v) {
    return __int_as_float(__builtin_amdgcn_ds_bpermute(byteaddr, __float_as_int(v)));
}

// cdf[m] (m=1..64) lives at lane m-1 of cdfv. Returns 4*lo with
// cdf[lo] <= uu < cdf[lo+1], lo in [0,63].
__device__ __forceinline__ int search6(float uu, float cdfv,
                                       float c8, float c16, float c24, float c32,
                                       float c40, float c48, float c56) {
    bool g1 = (c32 <= uu);
    int loB = g1 ? 128 : 0;
    float cA = g1 ? c48 : c16;
    bool g2 = (cA <= uu);
    loB += g2 ? 64 : 0;
    float pL = g1 ? c40 : c8;
    float pH = g1 ? c56 : c24;
    float cB = g2 ? pH : pL;
    loB += (cB <= uu) ? 32 : 0;
    float c = bperm(loB + 12, cdfv);   // cdf[lo+4] @ lane lo+3
    loB += (c <= uu) ? 16 : 0;
    c = bperm(loB + 4, cdfv);          // cdf[lo+2] @ lane lo+1
    loB += (c <= uu) ? 8 : 0;
    c = bperm(loB, cdfv);              // cdf[lo+1] @ lane lo
    loB += (c <= uu) ? 4 : 0;
    return loB;
}

// Everything for one ray given its loaded inputs; returns the packed store.
struct RayOut { fvec4 o4; };

__device__ __forceinline__ fvec4 ray_body(float w, float2 ti, float u0, float u1, float u2,
                                          int lane) {
    // maxblur
    float wm1 = dpp_old_f<DPP_WAVE_SHR1>(w, w);
    float wp1 = dpp_old_f<DPP_WAVE_SHL1>(w, w);
    float w2 = (fmaxf(wm1, w) + fmaxf(w, wp1)) * 0.5f + 0.01f;

    // inclusive scan (canonical gfx9 DPP, 6 ops)
    float scan = w2;
    scan = dpp_add<0x111, 0xf>(scan);
    scan = dpp_add<0x112, 0xf>(scan);
    scan = dpp_add<0x114, 0xf>(scan);
    scan = dpp_add<0x118, 0xf>(scan);
    scan = dpp_add<0x142, 0xa>(scan);
    scan = dpp_add<0x143, 0xc>(scan);

    // padding provably 0; fmin(1,.) drops <=1e-7 -> omitted
    float wsum = readlane_f(scan, 63);
    float cdfv = scan * __builtin_amdgcn_rcpf(wsum);
    if (lane == 63) cdfv = 1.0f;

    // per-bin linear coeffs: sample(u in bin l) = A[l] + B[l]*u
    float clo = dpp_old_f<DPP_WAVE_SHR1>(0.0f, cdfv);
    float nx  = dpp_old_f<DPP_WAVE_SHL1>(ti.y, ti.x);
    float dt  = nx - ti.x;
    float Bv  = dt * __builtin_amdgcn_rcpf(cdfv - clo);
    float Av  = ti.x - clo * Bv;

    // s[128]: ballot + popcount scalar path (hoisted off the tail)
    unsigned long long mask = __ballot(cdfv <= u2);
    int p = __popcll(mask);
    float s2 = readlane_f(Av, p) + readlane_f(Bv, p) * u2;

    // probes for the top 3 search levels
    float c8  = readlane_f(cdfv, 7),  c16 = readlane_f(cdfv, 15);
    float c24 = readlane_f(cdfv, 23), c32 = readlane_f(cdfv, 31);
    float c40 = readlane_f(cdfv, 39), c48 = readlane_f(cdfv, 47);
    float c56 = readlane_f(cdfv, 55);

    int lA = search6(u0, cdfv, c8, c16, c24, c32, c40, c48, c56);
    int lB = search6(u1, cdfv, c8, c16, c24, c32, c40, c48, c56);
    float s_a = bperm(lA, Av) + bperm(lA, Bv) * u0;     // s[2l]
    float s_b = bperm(lB, Av) + bperm(lB, Bv) * u1;     // s[2l+1]

    // s[2l+2] = next lane's s_a; lane63 -> s2
    float s_an = dpp_old_f<DPP_WAVE_SHL1>(s2, s_a);

    fvec4 o4 = { s_a, s_b, s_b, s_an };
    return o4;
}

__global__ __launch_bounds__(64 * WAVES_PER_BLOCK)
void sample_pdf_kernel(const float* __restrict__ weights,   // [R,64]
                       const float* __restrict__ t_inters,  // [R,64,2]
                       const float* __restrict__ u,         // [R,129]
                       float* __restrict__ out,             // [R,128,2]
                       int R) {
    const int lane  = threadIdx.x & 63;
    const int wave  = threadIdx.x >> 6;
    const int rayA  = (blockIdx.x * WAVES_PER_BLOCK + wave) * 2;
    const int rayB  = rayA + 1;
    if (rayB >= R + 1) return;   // R even; guard is effectively free

    // ---- both rays' loads issued together (one big vmcnt group)
    float  wA  = weights[(long)rayA * 64 + lane];
    float  wB  = weights[(long)rayB * 64 + lane];
    float2 tiA = ((const float2*)t_inters)[(long)rayA * 64 + lane];
    float2 tiB = ((const float2*)t_inters)[(long)rayB * 64 + lane];
    const float* ubA = u + (long)rayA * 129;
    const float* ubB = u + (long)rayB * 129;
    float u0A = ubA[2 * lane], u1A = ubA[2 * lane + 1], u2A = ubA[128];
    float u0B = ubB[2 * lane], u1B = ubB[2 * lane + 1], u2B = ubB[128];

    // ---- two independent chains; inlined twice so the scheduler interleaves
    fvec4 oA = ray_body(wA, tiA, u0A, u1A, u2A, lane);
    fvec4 oB = ray_body(wB, tiB, u0B, u1B, u2B, lane);

    __builtin_nontemporal_store(oA, &((fvec4*)out)[(long)rayA * 64 + lane]);
    __builtin_nontemporal_store(oB, &((fvec4*)out)[(long)rayB * 64 + lane]);
}

extern "C" void kernel_launch(void* const* d_in, const int* in_sizes, int n_in,
                              void* d_out, int out_size, void* d_ws, size_t ws_size,
                              hipStream_t stream) {
    const float* weights  = (const float*)d_in[0];
    const float* t_inters = (const float*)d_in[1];
    const float* u        = (const float*)d_in[2];
    float* out            = (float*)d_out;

    const int R = in_sizes[0] / 64;                       // 65536
    const int rays_per_block = WAVES_PER_BLOCK * 2;       // 8
    const int grid = (R + rays_per_block - 1) / rays_per_block;   // 8192
    sample_pdf_kernel<<<grid, 64 * WAVES_PER_BLOCK, 0, stream>>>(weights, t_inters, u, out, R);
}